// Round 1
// baseline (324.725 us; speedup 1.0000x reference)
//
#include <hip/hip_runtime.h>
#include <math.h>

#define C_WAY 10
#define K_SHOT 5
#define T_LEN 16
#define D_DIM 1024
#define NW 3
#define SEG_L 8

static inline int cdiv(int a, int b) { return (a + b - 1) / b; }

__device__ __forceinline__ float wsum(float v) {
#pragma unroll
    for (int o = 32; o; o >>= 1) v += __shfl_xor(v, o);
    return v;
}
__device__ __forceinline__ float wmax(float v) {
#pragma unroll
    for (int o = 32; o; o >>= 1) v = fmaxf(v, __shfl_xor(v, o));
    return v;
}
__device__ __forceinline__ float wsum8(float v) {
#pragma unroll
    for (int o = 4; o; o >>= 1) v += __shfl_xor(v, o);
    return v;
}
__device__ __forceinline__ float wmax8(float v) {
#pragma unroll
    for (int o = 4; o; o >>= 1) v = fmaxf(v, __shfl_xor(v, o));
    return v;
}

// proto[c,t,:] = mean_k support[(c*K+k), t, :]; pn_inv = 1/max(||proto row||, eps)
__global__ __launch_bounds__(256) void k_proto(const float* __restrict__ sup,
                                               float* __restrict__ proto,
                                               float* __restrict__ pn_inv) {
    int bid = blockIdx.x;  // c*16 + t
    int c = bid >> 4, t = bid & 15;
    int tid = threadIdx.x;
    float4 acc = {0.f, 0.f, 0.f, 0.f};
#pragma unroll
    for (int k = 0; k < K_SHOT; ++k) {
        float4 v = *(const float4*)&sup[(((size_t)(c * K_SHOT + k)) * T_LEN + t) * D_DIM + tid * 4];
        acc.x += v.x; acc.y += v.y; acc.z += v.z; acc.w += v.w;
    }
    const float s = 1.0f / (float)K_SHOT;
    acc.x *= s; acc.y *= s; acc.z *= s; acc.w *= s;
    *(float4*)&proto[(size_t)bid * D_DIM + tid * 4] = acc;
    float sq = acc.x * acc.x + acc.y * acc.y + acc.z * acc.z + acc.w * acc.w;
    __shared__ float red[4];
    sq = wsum(sq);
    if ((tid & 63) == 0) red[tid >> 6] = sq;
    __syncthreads();
    if (tid == 0) {
        float tot = red[0] + red[1] + red[2] + red[3];
        pn_inv[bid] = 1.0f / fmaxf(sqrtf(tot), 1e-12f);
    }
}

// inv[r] = 1/max(||X[r,:]||, eps); one wave per row
__global__ __launch_bounds__(256) void k_rowinv(const float* __restrict__ X,
                                                float* __restrict__ inv, int nrows) {
    int r = blockIdx.x * 4 + (threadIdx.x >> 6);
    int lane = threadIdx.x & 63;
    if (r >= nrows) return;
    float sq = 0.f;
#pragma unroll
    for (int i = 0; i < 4; ++i) {
        float4 v = *(const float4*)&X[(size_t)r * D_DIM + (i * 64 + lane) * 4];
        sq += v.x * v.x + v.y * v.y + v.z * v.z + v.w * v.w;
    }
    sq = wsum(sq);
    if (lane == 0) inv[r] = 1.0f / fmaxf(sqrtf(sq), 1e-12f);
}

// qcond[(q*3+v), :] = normalize(mean_l query[q, v*4+l, :])
__global__ __launch_bounds__(256) void k_qcond(const float* __restrict__ query,
                                               float* __restrict__ qcond) {
    int bid = blockIdx.x;  // q*3+v
    int q = bid / 3, v = bid % 3;
    int tid = threadIdx.x;
    float4 acc = {0.f, 0.f, 0.f, 0.f};
#pragma unroll
    for (int l = 0; l < SEG_L; ++l) {
        float4 x = *(const float4*)&query[((size_t)q * T_LEN + v * 4 + l) * D_DIM + tid * 4];
        acc.x += x.x; acc.y += x.y; acc.z += x.z; acc.w += x.w;
    }
    acc.x *= 0.125f; acc.y *= 0.125f; acc.z *= 0.125f; acc.w *= 0.125f;
    float sq = acc.x * acc.x + acc.y * acc.y + acc.z * acc.z + acc.w * acc.w;
    __shared__ float red[4];
    sq = wsum(sq);
    if ((tid & 63) == 0) red[tid >> 6] = sq;
    __syncthreads();
    float tot = red[0] + red[1] + red[2] + red[3];
    float scl = 1.0f / fmaxf(sqrtf(tot), 1e-12f);
    acc.x *= scl; acc.y *= scl; acc.z *= scl; acc.w *= scl;
    *(float4*)&qcond[(size_t)bid * D_DIM + tid * 4] = acc;
}

// scond[(c*3+w), :] = normalize(mean_{k,l} support[(c*K+k), w*4+l, :])
__global__ __launch_bounds__(256) void k_supcond(const float* __restrict__ sup,
                                                 float* __restrict__ scond) {
    int bid = blockIdx.x;  // c*3+w
    int c = bid / 3, w = bid % 3;
    int tid = threadIdx.x;
    float4 acc = {0.f, 0.f, 0.f, 0.f};
    for (int k = 0; k < K_SHOT; ++k)
#pragma unroll
        for (int l = 0; l < SEG_L; ++l) {
            float4 x = *(const float4*)&sup[(((size_t)(c * K_SHOT + k)) * T_LEN + w * 4 + l) * D_DIM + tid * 4];
            acc.x += x.x; acc.y += x.y; acc.z += x.z; acc.w += x.w;
        }
    const float s = 1.0f / 40.0f;
    acc.x *= s; acc.y *= s; acc.z *= s; acc.w *= s;
    float sq = acc.x * acc.x + acc.y * acc.y + acc.z * acc.z + acc.w * acc.w;
    __shared__ float red[4];
    sq = wsum(sq);
    if ((tid & 63) == 0) red[tid >> 6] = sq;
    __syncthreads();
    float tot = red[0] + red[1] + red[2] + red[3];
    float scl = 1.0f / fmaxf(sqrtf(tot), 1e-12f);
    acc.x *= scl; acc.y *= scl; acc.z *= scl; acc.w *= scl;
    *(float4*)&scond[(size_t)bid * D_DIM + tid * 4] = acc;
}

__global__ __launch_bounds__(256) void k_rowmaps(int* __restrict__ map_cls,
                                                 int* __restrict__ map_qseg, int Q) {
    int i = blockIdx.x * 256 + threadIdx.x;
    if (i < C_WAY * NW * 40) {
        int c = i / 120, rem = i % 120, w = rem / 40, n = rem % 40, k = n >> 3, l = n & 7;
        map_cls[i] = (c * K_SHOT + k) * T_LEN + w * 4 + l;
    }
    if (i < Q * NW * SEG_L) {
        int q = i / 24, rem = i % 24, v = rem / 8, l = rem & 7;
        map_qseg[i] = q * T_LEN + v * 4 + l;
    }
}

// C[b][m,n] = sum_k A[rowA(b,m), k] * B[rowB(b,n), k]   (A,B row-major, K inner)
// rowA(b,m) = mapA ? mapA[b*mapAs + m] : m   (batch only used with maps)
__global__ __launch_bounds__(256) void gemm_bt(const float* __restrict__ A,
                                               const float* __restrict__ B,
                                               float* __restrict__ C,
                                               int M, int N, int K,
                                               const int* __restrict__ mapA, int mapAs,
                                               const int* __restrict__ mapB, int mapBs,
                                               long cstride) {
    __shared__ __align__(16) float As[16][68];
    __shared__ __align__(16) float Bs[16][68];
    int b = blockIdx.z;
    const int* mA = mapA ? mapA + (size_t)b * mapAs : nullptr;
    const int* mB = mapB ? mapB + (size_t)b * mapBs : nullptr;
    float* Cb = C + (size_t)b * cstride;
    int m0 = blockIdx.x * 64, n0 = blockIdx.y * 64;
    int tid = threadIdx.x;
    int tx = tid & 15, ty = tid >> 4;
    int lr = tid >> 2;         // 0..63 tile row for staging
    int lk = (tid & 3) * 4;    // k offset for staging
    long arow = -1, brow = -1;
    if (m0 + lr < M) arow = mA ? mA[m0 + lr] : (m0 + lr);
    if (n0 + lr < N) brow = mB ? mB[n0 + lr] : (n0 + lr);
    float acc[4][4] = {};
    for (int k0 = 0; k0 < K; k0 += 16) {
        float4 av = {0.f, 0.f, 0.f, 0.f}, bv = {0.f, 0.f, 0.f, 0.f};
        if (arow >= 0) av = *(const float4*)&A[(size_t)arow * K + k0 + lk];
        if (brow >= 0) bv = *(const float4*)&B[(size_t)brow * K + k0 + lk];
        __syncthreads();
        As[lk + 0][lr] = av.x; As[lk + 1][lr] = av.y; As[lk + 2][lr] = av.z; As[lk + 3][lr] = av.w;
        Bs[lk + 0][lr] = bv.x; Bs[lk + 1][lr] = bv.y; Bs[lk + 2][lr] = bv.z; Bs[lk + 3][lr] = bv.w;
        __syncthreads();
#pragma unroll
        for (int k = 0; k < 16; ++k) {
            float4 a4 = *(const float4*)&As[k][ty * 4];
            float4 b4 = *(const float4*)&Bs[k][tx * 4];
            float a[4] = {a4.x, a4.y, a4.z, a4.w};
            float bb[4] = {b4.x, b4.y, b4.z, b4.w};
#pragma unroll
            for (int i = 0; i < 4; ++i)
#pragma unroll
                for (int j = 0; j < 4; ++j) acc[i][j] = fmaf(a[i], bb[j], acc[i][j]);
        }
    }
#pragma unroll
    for (int i = 0; i < 4; ++i) {
        int m = m0 + ty * 4 + i;
        if (m >= M) break;
#pragma unroll
        for (int j = 0; j < 4; ++j) {
            int n = n0 + tx * 4 + j;
            if (n < N) Cb[(size_t)m * N + n] = acc[i][j];
        }
    }
}

// Gq[(q*3+v)][n*8+m] = dot(q_seg[q,v,n,:], q_seg[q,v,m,:]); one wave per block
__global__ __launch_bounds__(64) void k_gq(const float* __restrict__ query,
                                           float* __restrict__ Gq) {
    __shared__ __align__(16) float s[8 * 1028];
    int bid = blockIdx.x;  // q*3+v
    int q = bid / 3, v = bid % 3;
    int lane = threadIdx.x;
#pragma unroll
    for (int i = 0; i < 32; ++i) {
        int f4 = i * 64 + lane;  // 0..2047 float4 index
        int row = f4 >> 8, c4 = f4 & 255;
        float4 val = *(const float4*)&query[((size_t)q * T_LEN + v * 4 + row) * D_DIM + c4 * 4];
        *(float4*)&s[row * 1028 + c4 * 4] = val;
    }
    __syncthreads();
    int n = lane >> 3, m = lane & 7;
    const float* ra = &s[n * 1028];
    const float* rb = &s[m * 1028];
    float acc = 0.f;
    for (int t = 0; t < 256; ++t) {
        float4 a = *(const float4*)&ra[t * 4];
        float4 b = *(const float4*)&rb[t * 4];
        acc = fmaf(a.x, b.x, acc); acc = fmaf(a.y, b.y, acc);
        acc = fmaf(a.z, b.z, acc); acc = fmaf(a.w, b.w, acc);
    }
    Gq[(size_t)bid * 64 + lane] = acc;
}

// global_score[q, c] from SIM (raw dots) with row/col scales; block per q
__global__ __launch_bounds__(256) void k_greduce(const float* __restrict__ SIM,
                                                 const float* __restrict__ qrow_inv,
                                                 const float* __restrict__ pn_inv,
                                                 float* __restrict__ gscore) {
    __shared__ float d[16 * 160];
    __shared__ float rmin[160], cmin[160];
    int q = blockIdx.x, tid = threadIdx.x;
#pragma unroll
    for (int i = 0; i < 10; ++i) {
        int idx = tid + i * 256;  // 0..2559
        int t = idx / 160, col = idx % 160;
        float v = SIM[((size_t)(q * 16 + t)) * 160 + col] * qrow_inv[q * 16 + t] * pn_inv[col];
        d[idx] = 1.0f - v;
    }
    __syncthreads();
    if (tid < 160) {
        int c = tid / 16, t = tid % 16;
        float mn = 3.4e38f;
#pragma unroll
        for (int s2 = 0; s2 < 16; ++s2) mn = fminf(mn, d[t * 160 + c * 16 + s2]);
        rmin[tid] = mn;
        int s = t;
        mn = 3.4e38f;
#pragma unroll
        for (int t2 = 0; t2 < 16; ++t2) mn = fminf(mn, d[t2 * 160 + c * 16 + s]);
        cmin[tid] = mn;
    }
    __syncthreads();
    if (tid < 10) {
        float sum = 0.f;
#pragma unroll
        for (int t = 0; t < 16; ++t) sum += rmin[tid * 16 + t] + cmin[tid * 16 + t];
        gscore[q * 10 + tid] = -sum;
    }
}

// final fused scoring: one wave per (q,c)
__global__ __launch_bounds__(64) void k_final(const float* __restrict__ S_raw,
                                              const float* __restrict__ Q_raw,
                                              const float* __restrict__ G_sup,
                                              const float* __restrict__ G_q,
                                              const float* __restrict__ gscore,
                                              const float* __restrict__ fusion,
                                              float* __restrict__ out) {
    int bid = blockIdx.x;  // q*10 + c
    int q = bid / 10, c = bid % 10;
    int lane = threadIdx.x;
    const float inv_sqrt_d = 0.03125f;  // 1/sqrt(1024)
    float b1s = -3.4e38f, b2s = -3.4e38f;
    float b1q = -3.4e38f, b2q = -3.4e38f;
    for (int vw = 0; vw < 9; ++vw) {
        int v = vw / 3, w = vw % 3;
        // ---- s2q: softmax over 40 support tokens ----
        bool act = lane < 40;
        float raw = act ? S_raw[((size_t)(q * 3 + v)) * 1200 + (c * 3 + w) * 40 + lane] : 0.f;
        float x = act ? raw * inv_sqrt_d : -3.4e38f;
        float mx = wmax(x);
        float e = act ? __expf(x - mx) : 0.f;
        float ssum = wsum(e);
        float attn = act ? e / ssum : 0.f;
        float dotqp = wsum(attn * raw);
        float inner = 0.f;
        const float* G = &G_sup[(size_t)(c * 3 + w) * 1600];
        for (int m = 0; m < 40; ++m) {
            float am = __shfl(attn, m);
            float g = act ? G[m * 40 + lane] : 0.f;
            inner = fmaf(am, g, inner);
        }
        float nrm2 = wsum(attn * inner);
        float sc_s2q = dotqp / fmaxf(sqrtf(fmaxf(nrm2, 0.f)), 1e-12f);
        // ---- q2s: softmax over 8 query tokens (lanes 0..7, group-of-8 reduces) ----
        bool act8 = lane < 8;
        float qraw = act8 ? Q_raw[((size_t)((q * 3 + v) * 8 + lane)) * 30 + (c * 3 + w)] : 0.f;
        float x8 = act8 ? qraw * inv_sqrt_d : -3.4e38f;
        float mx8 = wmax8(x8);
        float e8 = act8 ? __expf(x8 - mx8) : 0.f;
        float s8 = wsum8(e8);
        float attn8 = act8 ? e8 / s8 : 0.f;
        float dotq2 = wsum8(attn8 * qraw);
        float inner8 = 0.f;
        const float* Gqp = &G_q[(size_t)(q * 3 + v) * 64];
        for (int m = 0; m < 8; ++m) {
            float am = __shfl(attn8, m);
            float g = act8 ? Gqp[m * 8 + lane] : 0.f;
            inner8 = fmaf(am, g, inner8);
        }
        float nrm28 = wsum8(attn8 * inner8);
        float sc_q2s = dotq2 / fmaxf(sqrtf(fmaxf(nrm28, 0.f)), 1e-12f);
        sc_q2s = __shfl(sc_q2s, 0);
        if (sc_s2q > b1s) { b2s = b1s; b1s = sc_s2q; } else if (sc_s2q > b2s) b2s = sc_s2q;
        if (sc_q2s > b1q) { b2q = b1q; b1q = sc_q2s; } else if (sc_q2s > b2q) b2q = sc_q2s;
    }
    if (lane == 0) {
        float seg = 0.5f * (0.5f * (b1s + b2s) + 0.5f * (b1q + b2q));
        float l0 = fusion[0], l1 = fusion[1];
        float mm = fmaxf(l0, l1);
        float e0 = __expf(l0 - mm), e1 = __expf(l1 - mm);
        float f0 = e0 / (e0 + e1), f1 = e1 / (e0 + e1);
        out[bid] = f0 * gscore[bid] + f1 * seg;
    }
}

extern "C" void kernel_launch(void* const* d_in, const int* in_sizes, int n_in,
                              void* d_out, int out_size, void* d_ws, size_t ws_size,
                              hipStream_t stream) {
    const float* sup = (const float*)d_in[0];    // [50,16,1024]
    const float* query = (const float*)d_in[1];  // [400,16,1024]
    const float* fusion = (const float*)d_in[2]; // [2]
    float* out = (float*)d_out;                  // [400,10]
    const int Q = in_sizes[1] / (T_LEN * D_DIM); // 400

    float* w = (float*)d_ws;
    size_t off = 0;
    float* proto = w + off;     off += (size_t)C_WAY * T_LEN * D_DIM;
    float* qcond = w + off;     off += (size_t)Q * NW * D_DIM;
    float* scond = w + off;     off += (size_t)C_WAY * NW * D_DIM;
    float* pn_inv = w + off;    off += C_WAY * T_LEN;
    float* qrow_inv = w + off;  off += (size_t)Q * T_LEN;
    float* gscore = w + off;    off += (size_t)Q * C_WAY;
    float* Gsup = w + off;      off += C_WAY * NW * 40 * 40;
    float* Gq = w + off;        off += (size_t)Q * NW * 64;
    float* SIM = w + off;       off += (size_t)Q * T_LEN * C_WAY * T_LEN;
    float* Sraw = w + off;      off += (size_t)Q * NW * C_WAY * NW * 40;
    float* Qraw = w + off;      off += (size_t)Q * NW * SEG_L * C_WAY * NW;
    int* map_cls = (int*)(w + off);  off += C_WAY * NW * 40;
    int* map_qseg = (int*)(w + off); off += (size_t)Q * NW * SEG_L;
    (void)ws_size; (void)n_in; (void)out_size;

    // precompute
    k_rowmaps<<<cdiv(Q * NW * SEG_L, 256), 256, 0, stream>>>(map_cls, map_qseg, Q);
    k_proto<<<C_WAY * T_LEN, 256, 0, stream>>>(sup, proto, pn_inv);
    k_rowinv<<<Q * T_LEN / 4, 256, 0, stream>>>(query, qrow_inv, Q * T_LEN);
    k_qcond<<<Q * NW, 256, 0, stream>>>(query, qcond);
    k_supcond<<<C_WAY * NW, 256, 0, stream>>>(sup, scond);

    // SIM = query · protoᵀ  [Q*16, 160]
    {
        dim3 g(cdiv(Q * T_LEN, 64), cdiv(C_WAY * T_LEN, 64), 1);
        gemm_bt<<<g, 256, 0, stream>>>(query, proto, SIM, Q * T_LEN, C_WAY * T_LEN, D_DIM,
                                       nullptr, 0, nullptr, 0, 0);
    }
    // S_raw = qcond · cls_supᵀ  [Q*3, 1200]  (cls_sup = support rows via map)
    {
        dim3 g(cdiv(Q * NW, 64), cdiv(C_WAY * NW * 40, 64), 1);
        gemm_bt<<<g, 256, 0, stream>>>(qcond, sup, Sraw, Q * NW, C_WAY * NW * 40, D_DIM,
                                       nullptr, 0, map_cls, 0, 0);
    }
    // Q_raw = q_seg · scondᵀ  [Q*24, 30]  (q_seg = query rows via map)
    {
        dim3 g(cdiv(Q * NW * SEG_L, 64), cdiv(C_WAY * NW, 64), 1);
        gemm_bt<<<g, 256, 0, stream>>>(query, scond, Qraw, Q * NW * SEG_L, C_WAY * NW, D_DIM,
                                       map_qseg, 0, nullptr, 0, 0);
    }
    // G_sup[b] = cls_sup[b] · cls_sup[b]ᵀ, b over 30 (c,w), 40×40 each
    {
        dim3 g(1, 1, C_WAY * NW);
        gemm_bt<<<g, 256, 0, stream>>>(sup, sup, Gsup, 40, 40, D_DIM,
                                       map_cls, 40, map_cls, 40, 1600);
    }
    k_gq<<<Q * NW, 64, 0, stream>>>(query, Gq);
    k_greduce<<<Q, 256, 0, stream>>>(SIM, qrow_inv, pn_inv, gscore);
    k_final<<<Q * C_WAY, 64, 0, stream>>>(Sraw, Qraw, Gsup, Gq, gscore, fusion, out);
}

// Round 2
// 142.828 us; speedup vs baseline: 2.2735x; 2.2735x over previous
//
#include <hip/hip_runtime.h>
#include <math.h>

#define C_WAY 10
#define K_SHOT 5
#define T_LEN 16
#define D_DIM 1024
#define NW 3
#define SEG_L 8

typedef __attribute__((ext_vector_type(8))) __bf16 bf16x8;
typedef __attribute__((ext_vector_type(4))) float f32x4;

static inline int cdiv(int a, int b) { return (a + b - 1) / b; }

__device__ __forceinline__ unsigned short f2bf(float f) {
    unsigned int u = __float_as_uint(f);
    u += 0x7fffu + ((u >> 16) & 1u);
    return (unsigned short)(u >> 16);
}

__device__ __forceinline__ float wsum(float v) {
#pragma unroll
    for (int o = 32; o; o >>= 1) v += __shfl_xor(v, o);
    return v;
}
__device__ __forceinline__ float wmax(float v) {
#pragma unroll
    for (int o = 32; o; o >>= 1) v = fmaxf(v, __shfl_xor(v, o));
    return v;
}
__device__ __forceinline__ float wsum8(float v) {
#pragma unroll
    for (int o = 4; o; o >>= 1) v += __shfl_xor(v, o);
    return v;
}
__device__ __forceinline__ float wmax8(float v) {
#pragma unroll
    for (int o = 4; o; o >>= 1) v = fmaxf(v, __shfl_xor(v, o));
    return v;
}

// query row -> bf16 copy + 1/max(||row||,eps); one block per row
__global__ __launch_bounds__(256) void k_prep_query(const float* __restrict__ q,
                                                    unsigned short* __restrict__ qbf,
                                                    float* __restrict__ qrow_inv) {
    int r = blockIdx.x, t = threadIdx.x;
    float4 v = *(const float4*)&q[(size_t)r * D_DIM + t * 4];
    ushort4 b = {f2bf(v.x), f2bf(v.y), f2bf(v.z), f2bf(v.w)};
    *(ushort4*)&qbf[(size_t)r * D_DIM + t * 4] = b;
    float sq = v.x * v.x + v.y * v.y + v.z * v.z + v.w * v.w;
    __shared__ float red[4];
    sq = wsum(sq);
    if ((t & 63) == 0) red[t >> 6] = sq;
    __syncthreads();
    if (t == 0) qrow_inv[r] = 1.0f / fmaxf(sqrtf(red[0] + red[1] + red[2] + red[3]), 1e-12f);
}

// support row -> bf16 copy
__global__ __launch_bounds__(256) void k_prep_sup(const float* __restrict__ s,
                                                  unsigned short* __restrict__ sbf) {
    int r = blockIdx.x, t = threadIdx.x;
    float4 v = *(const float4*)&s[(size_t)r * D_DIM + t * 4];
    ushort4 b = {f2bf(v.x), f2bf(v.y), f2bf(v.z), f2bf(v.w)};
    *(ushort4*)&sbf[(size_t)r * D_DIM + t * 4] = b;
}

// proto[c,t,:] (bf16) = mean_k support[(c*K+k), t, :]; pn_inv = 1/max(||proto row||, eps)
__global__ __launch_bounds__(256) void k_proto(const float* __restrict__ sup,
                                               unsigned short* __restrict__ protobf,
                                               float* __restrict__ pn_inv) {
    int bid = blockIdx.x;  // c*16 + t
    int c = bid >> 4, t = bid & 15;
    int tid = threadIdx.x;
    float4 acc = {0.f, 0.f, 0.f, 0.f};
#pragma unroll
    for (int k = 0; k < K_SHOT; ++k) {
        float4 v = *(const float4*)&sup[(((size_t)(c * K_SHOT + k)) * T_LEN + t) * D_DIM + tid * 4];
        acc.x += v.x; acc.y += v.y; acc.z += v.z; acc.w += v.w;
    }
    const float s = 1.0f / (float)K_SHOT;
    acc.x *= s; acc.y *= s; acc.z *= s; acc.w *= s;
    ushort4 b = {f2bf(acc.x), f2bf(acc.y), f2bf(acc.z), f2bf(acc.w)};
    *(ushort4*)&protobf[(size_t)bid * D_DIM + tid * 4] = b;
    float sq = acc.x * acc.x + acc.y * acc.y + acc.z * acc.z + acc.w * acc.w;
    __shared__ float red[4];
    sq = wsum(sq);
    if ((tid & 63) == 0) red[tid >> 6] = sq;
    __syncthreads();
    if (tid == 0) {
        float tot = red[0] + red[1] + red[2] + red[3];
        pn_inv[bid] = 1.0f / fmaxf(sqrtf(tot), 1e-12f);
    }
}

// qcond[(q*3+v), :] (bf16) = normalize(mean_l query[q, v*4+l, :])
__global__ __launch_bounds__(256) void k_qcond(const float* __restrict__ query,
                                               unsigned short* __restrict__ qcondbf) {
    int bid = blockIdx.x;  // q*3+v
    int q = bid / 3, v = bid % 3;
    int tid = threadIdx.x;
    float4 acc = {0.f, 0.f, 0.f, 0.f};
#pragma unroll
    for (int l = 0; l < SEG_L; ++l) {
        float4 x = *(const float4*)&query[((size_t)q * T_LEN + v * 4 + l) * D_DIM + tid * 4];
        acc.x += x.x; acc.y += x.y; acc.z += x.z; acc.w += x.w;
    }
    acc.x *= 0.125f; acc.y *= 0.125f; acc.z *= 0.125f; acc.w *= 0.125f;
    float sq = acc.x * acc.x + acc.y * acc.y + acc.z * acc.z + acc.w * acc.w;
    __shared__ float red[4];
    sq = wsum(sq);
    if ((tid & 63) == 0) red[tid >> 6] = sq;
    __syncthreads();
    float tot = red[0] + red[1] + red[2] + red[3];
    float scl = 1.0f / fmaxf(sqrtf(tot), 1e-12f);
    ushort4 b = {f2bf(acc.x * scl), f2bf(acc.y * scl), f2bf(acc.z * scl), f2bf(acc.w * scl)};
    *(ushort4*)&qcondbf[(size_t)bid * D_DIM + tid * 4] = b;
}

// scond[(c*3+w), :] (bf16) = normalize(mean_{k,l} support[(c*K+k), w*4+l, :])
__global__ __launch_bounds__(256) void k_supcond(const float* __restrict__ sup,
                                                 unsigned short* __restrict__ scondbf) {
    int bid = blockIdx.x;  // c*3+w
    int c = bid / 3, w = bid % 3;
    int tid = threadIdx.x;
    float4 acc = {0.f, 0.f, 0.f, 0.f};
    for (int k = 0; k < K_SHOT; ++k)
#pragma unroll
        for (int l = 0; l < SEG_L; ++l) {
            float4 x = *(const float4*)&sup[(((size_t)(c * K_SHOT + k)) * T_LEN + w * 4 + l) * D_DIM + tid * 4];
            acc.x += x.x; acc.y += x.y; acc.z += x.z; acc.w += x.w;
        }
    const float s = 1.0f / 40.0f;
    acc.x *= s; acc.y *= s; acc.z *= s; acc.w *= s;
    float sq = acc.x * acc.x + acc.y * acc.y + acc.z * acc.z + acc.w * acc.w;
    __shared__ float red[4];
    sq = wsum(sq);
    if ((tid & 63) == 0) red[tid >> 6] = sq;
    __syncthreads();
    float tot = red[0] + red[1] + red[2] + red[3];
    float scl = 1.0f / fmaxf(sqrtf(tot), 1e-12f);
    ushort4 b = {f2bf(acc.x * scl), f2bf(acc.y * scl), f2bf(acc.z * scl), f2bf(acc.w * scl)};
    *(ushort4*)&scondbf[(size_t)bid * D_DIM + tid * 4] = b;
}

__global__ __launch_bounds__(256) void k_rowmaps(int* __restrict__ map_cls,
                                                 int* __restrict__ map_qseg, int Q) {
    int i = blockIdx.x * 256 + threadIdx.x;
    if (i < C_WAY * NW * 40) {
        int c = i / 120, rem = i % 120, w = rem / 40, n = rem % 40, k = n >> 3, l = n & 7;
        map_cls[i] = (c * K_SHOT + k) * T_LEN + w * 4 + l;
    }
    if (i < Q * NW * SEG_L) {
        int q = i / 24, rem = i % 24, v = rem / 8, l = rem & 7;
        map_qseg[i] = q * T_LEN + v * 4 + l;
    }
}

// C[b][m,n] = sum_k A[rowA(b,m), k] * B[rowB(b,n), k]  (bf16 inputs, fp32 accum)
// 64x64 tile, K-step 64, 4 waves -> 32x32 quadrants of 2x2 mfma_f32_16x16x32_bf16.
__global__ __launch_bounds__(256) void gemm_mfma(const unsigned short* __restrict__ A,
                                                 const unsigned short* __restrict__ B,
                                                 float* __restrict__ C,
                                                 int M, int N, int K,
                                                 const int* __restrict__ mapA, int mapAs,
                                                 const int* __restrict__ mapB, int mapBs,
                                                 long cstride) {
    __shared__ __align__(16) unsigned short As[64][72];  // pad to 72 (144B rows)
    __shared__ __align__(16) unsigned short Bs[64][72];
    int b = blockIdx.z;
    float* Cb = C + (size_t)b * cstride;
    int m0 = blockIdx.x * 64, n0 = blockIdx.y * 64;
    int t = threadIdx.x;
    int srow = t >> 2, sk = (t & 3) * 8;  // staging: 4 lanes cover one row's 64 k
    long ga = -1, gb = -1;
    if (m0 + srow < M) ga = mapA ? mapA[(size_t)b * mapAs + m0 + srow] : (m0 + srow);
    if (n0 + srow < N) gb = mapB ? mapB[(size_t)b * mapBs + n0 + srow] : (n0 + srow);

    int w = t >> 6, l = t & 63;
    int rowbase = (w >> 1) * 32, colbase = (w & 1) * 32;
    int fr = l & 15, fc = l >> 4;

    f32x4 acc[2][2] = {};

    uint4 ra0 = {0, 0, 0, 0}, ra1 = {0, 0, 0, 0}, rb0 = {0, 0, 0, 0}, rb1 = {0, 0, 0, 0};
    if (ga >= 0) {
        ra0 = *(const uint4*)&A[(size_t)ga * K + sk];
        ra1 = *(const uint4*)&A[(size_t)ga * K + sk + 32];
    }
    if (gb >= 0) {
        rb0 = *(const uint4*)&B[(size_t)gb * K + sk];
        rb1 = *(const uint4*)&B[(size_t)gb * K + sk + 32];
    }
    for (int k0 = 0; k0 < K; k0 += 64) {
        __syncthreads();  // previous step's LDS reads done
        *(uint4*)&As[srow][sk] = ra0;
        *(uint4*)&As[srow][sk + 32] = ra1;
        *(uint4*)&Bs[srow][sk] = rb0;
        *(uint4*)&Bs[srow][sk + 32] = rb1;
        __syncthreads();
        int kn = k0 + 64;
        if (kn < K) {  // prefetch next step (overlaps with MFMA below)
            if (ga >= 0) {
                ra0 = *(const uint4*)&A[(size_t)ga * K + kn + sk];
                ra1 = *(const uint4*)&A[(size_t)ga * K + kn + sk + 32];
            }
            if (gb >= 0) {
                rb0 = *(const uint4*)&B[(size_t)gb * K + kn + sk];
                rb1 = *(const uint4*)&B[(size_t)gb * K + kn + sk + 32];
            }
        }
#pragma unroll
        for (int kk = 0; kk < 2; ++kk) {
            bf16x8 a0 = *(const bf16x8*)&As[rowbase + fr][kk * 32 + fc * 8];
            bf16x8 a1 = *(const bf16x8*)&As[rowbase + 16 + fr][kk * 32 + fc * 8];
            bf16x8 b0 = *(const bf16x8*)&Bs[colbase + fr][kk * 32 + fc * 8];
            bf16x8 b1 = *(const bf16x8*)&Bs[colbase + 16 + fr][kk * 32 + fc * 8];
            acc[0][0] = __builtin_amdgcn_mfma_f32_16x16x32_bf16(a0, b0, acc[0][0], 0, 0, 0);
            acc[0][1] = __builtin_amdgcn_mfma_f32_16x16x32_bf16(a0, b1, acc[0][1], 0, 0, 0);
            acc[1][0] = __builtin_amdgcn_mfma_f32_16x16x32_bf16(a1, b0, acc[1][0], 0, 0, 0);
            acc[1][1] = __builtin_amdgcn_mfma_f32_16x16x32_bf16(a1, b1, acc[1][1], 0, 0, 0);
        }
    }
    // C/D layout: col = lane&15, row = (lane>>4)*4 + reg
    int crow = fc * 4, ccol = fr;
#pragma unroll
    for (int fi = 0; fi < 2; ++fi)
#pragma unroll
        for (int fj = 0; fj < 2; ++fj)
#pragma unroll
            for (int j = 0; j < 4; ++j) {
                int m = m0 + rowbase + fi * 16 + crow + j;
                int n = n0 + colbase + fj * 16 + ccol;
                if (m < M && n < N) Cb[(size_t)m * N + n] = acc[fi][fj][j];
            }
}

// Gq[(q*3+v)][n*8+m] = dot(q_seg[q,v,n,:], q_seg[q,v,m,:]); one wave per block
__global__ __launch_bounds__(64) void k_gq(const float* __restrict__ query,
                                           float* __restrict__ Gq) {
    __shared__ __align__(16) float s[8 * 1028];
    int bid = blockIdx.x;  // q*3+v
    int q = bid / 3, v = bid % 3;
    int lane = threadIdx.x;
#pragma unroll
    for (int i = 0; i < 32; ++i) {
        int f4 = i * 64 + lane;
        int row = f4 >> 8, c4 = f4 & 255;
        float4 val = *(const float4*)&query[((size_t)q * T_LEN + v * 4 + row) * D_DIM + c4 * 4];
        *(float4*)&s[row * 1028 + c4 * 4] = val;
    }
    __syncthreads();
    int n = lane >> 3, m = lane & 7;
    const float* ra = &s[n * 1028];
    const float* rb = &s[m * 1028];
    float acc = 0.f;
    for (int t = 0; t < 256; ++t) {
        float4 a = *(const float4*)&ra[t * 4];
        float4 b = *(const float4*)&rb[t * 4];
        acc = fmaf(a.x, b.x, acc); acc = fmaf(a.y, b.y, acc);
        acc = fmaf(a.z, b.z, acc); acc = fmaf(a.w, b.w, acc);
    }
    Gq[(size_t)bid * 64 + lane] = acc;
}

// global_score[q, c] from SIM (raw dots) with row/col scales; block per q
__global__ __launch_bounds__(256) void k_greduce(const float* __restrict__ SIM,
                                                 const float* __restrict__ qrow_inv,
                                                 const float* __restrict__ pn_inv,
                                                 float* __restrict__ gscore) {
    __shared__ float d[16 * 160];
    __shared__ float rmin[160], cmin[160];
    int q = blockIdx.x, tid = threadIdx.x;
#pragma unroll
    for (int i = 0; i < 10; ++i) {
        int idx = tid + i * 256;
        int t = idx / 160, col = idx % 160;
        float v = SIM[((size_t)(q * 16 + t)) * 160 + col] * qrow_inv[q * 16 + t] * pn_inv[col];
        d[idx] = 1.0f - v;
    }
    __syncthreads();
    if (tid < 160) {
        int c = tid / 16, t = tid % 16;
        float mn = 3.4e38f;
#pragma unroll
        for (int s2 = 0; s2 < 16; ++s2) mn = fminf(mn, d[t * 160 + c * 16 + s2]);
        rmin[tid] = mn;
        int s = t;
        mn = 3.4e38f;
#pragma unroll
        for (int t2 = 0; t2 < 16; ++t2) mn = fminf(mn, d[t2 * 160 + c * 16 + s]);
        cmin[tid] = mn;
    }
    __syncthreads();
    if (tid < 10) {
        float sum = 0.f;
#pragma unroll
        for (int t = 0; t < 16; ++t) sum += rmin[tid * 16 + t] + cmin[tid * 16 + t];
        gscore[q * 10 + tid] = -sum;
    }
}

// final fused scoring: one wave per (q,c)
__global__ __launch_bounds__(64) void k_final(const float* __restrict__ S_raw,
                                              const float* __restrict__ Q_raw,
                                              const float* __restrict__ G_sup,
                                              const float* __restrict__ G_q,
                                              const float* __restrict__ gscore,
                                              const float* __restrict__ fusion,
                                              float* __restrict__ out) {
    int bid = blockIdx.x;  // q*10 + c
    int q = bid / 10, c = bid % 10;
    int lane = threadIdx.x;
    const float inv_sqrt_d = 0.03125f;  // 1/sqrt(1024)
    float b1s = -3.4e38f, b2s = -3.4e38f;
    float b1q = -3.4e38f, b2q = -3.4e38f;
    for (int vw = 0; vw < 9; ++vw) {
        int v = vw / 3, w = vw % 3;
        // ---- s2q: softmax over 40 support tokens ----
        bool act = lane < 40;
        float raw = act ? S_raw[((size_t)(q * 3 + v)) * 1200 + (c * 3 + w) * 40 + lane] : 0.f;
        float x = act ? raw * inv_sqrt_d : -3.4e38f;
        float mx = wmax(x);
        float e = act ? __expf(x - mx) : 0.f;
        float ssum = wsum(e);
        float attn = act ? e / ssum : 0.f;
        float dotqp = wsum(attn * raw);
        float inner = 0.f;
        const float* G = &G_sup[(size_t)(c * 3 + w) * 1600];
        for (int m = 0; m < 40; ++m) {
            float am = __shfl(attn, m);
            float g = act ? G[m * 40 + lane] : 0.f;
            inner = fmaf(am, g, inner);
        }
        float nrm2 = wsum(attn * inner);
        float sc_s2q = dotqp / fmaxf(sqrtf(fmaxf(nrm2, 0.f)), 1e-12f);
        // ---- q2s: softmax over 8 query tokens (lanes 0..7, group-of-8 reduces) ----
        bool act8 = lane < 8;
        float qraw = act8 ? Q_raw[((size_t)((q * 3 + v) * 8 + lane)) * 30 + (c * 3 + w)] : 0.f;
        float x8 = act8 ? qraw * inv_sqrt_d : -3.4e38f;
        float mx8 = wmax8(x8);
        float e8 = act8 ? __expf(x8 - mx8) : 0.f;
        float s8 = wsum8(e8);
        float attn8 = act8 ? e8 / s8 : 0.f;
        float dotq2 = wsum8(attn8 * qraw);
        float inner8 = 0.f;
        const float* Gqp = &G_q[(size_t)(q * 3 + v) * 64];
        for (int m = 0; m < 8; ++m) {
            float am = __shfl(attn8, m);
            float g = act8 ? Gqp[m * 8 + lane] : 0.f;
            inner8 = fmaf(am, g, inner8);
        }
        float nrm28 = wsum8(attn8 * inner8);
        float sc_q2s = dotq2 / fmaxf(sqrtf(fmaxf(nrm28, 0.f)), 1e-12f);
        sc_q2s = __shfl(sc_q2s, 0);
        if (sc_s2q > b1s) { b2s = b1s; b1s = sc_s2q; } else if (sc_s2q > b2s) b2s = sc_s2q;
        if (sc_q2s > b1q) { b2q = b1q; b1q = sc_q2s; } else if (sc_q2s > b2q) b2q = sc_q2s;
    }
    if (lane == 0) {
        float seg = 0.5f * (0.5f * (b1s + b2s) + 0.5f * (b1q + b2q));
        float l0 = fusion[0], l1 = fusion[1];
        float mm = fmaxf(l0, l1);
        float e0 = __expf(l0 - mm), e1 = __expf(l1 - mm);
        float f0 = e0 / (e0 + e1), f1 = e1 / (e0 + e1);
        out[bid] = f0 * gscore[bid] + f1 * seg;
    }
}

extern "C" void kernel_launch(void* const* d_in, const int* in_sizes, int n_in,
                              void* d_out, int out_size, void* d_ws, size_t ws_size,
                              hipStream_t stream) {
    const float* sup = (const float*)d_in[0];    // [50,16,1024]
    const float* query = (const float*)d_in[1];  // [400,16,1024]
    const float* fusion = (const float*)d_in[2]; // [2]
    float* out = (float*)d_out;                  // [400,10]
    const int Q = in_sizes[1] / (T_LEN * D_DIM); // 400

    float* w = (float*)d_ws;
    size_t off = 0;
    unsigned short* qbf = (unsigned short*)(w + off);     off += (size_t)Q * T_LEN * D_DIM / 2;
    unsigned short* supbf = (unsigned short*)(w + off);   off += (size_t)C_WAY * K_SHOT * T_LEN * D_DIM / 2;
    unsigned short* protobf = (unsigned short*)(w + off); off += (size_t)C_WAY * T_LEN * D_DIM / 2;
    unsigned short* qcondbf = (unsigned short*)(w + off); off += (size_t)Q * NW * D_DIM / 2;
    unsigned short* scondbf = (unsigned short*)(w + off); off += (size_t)C_WAY * NW * D_DIM / 2 + 8;
    float* pn_inv = w + off;    off += C_WAY * T_LEN;
    float* qrow_inv = w + off;  off += (size_t)Q * T_LEN;
    float* gscore = w + off;    off += (size_t)Q * C_WAY;
    float* Gsup = w + off;      off += C_WAY * NW * 40 * 40;
    float* Gq = w + off;        off += (size_t)Q * NW * 64;
    float* SIM = w + off;       off += (size_t)Q * T_LEN * C_WAY * T_LEN;
    float* Sraw = w + off;      off += (size_t)Q * NW * C_WAY * NW * 40;
    float* Qraw = w + off;      off += (size_t)Q * NW * SEG_L * C_WAY * NW;
    int* map_cls = (int*)(w + off);  off += C_WAY * NW * 40;
    int* map_qseg = (int*)(w + off); off += (size_t)Q * NW * SEG_L;
    (void)ws_size; (void)n_in; (void)out_size;

    // precompute / bf16 conversion
    k_rowmaps<<<cdiv(Q * NW * SEG_L, 256), 256, 0, stream>>>(map_cls, map_qseg, Q);
    k_prep_query<<<Q * T_LEN, 256, 0, stream>>>(query, qbf, qrow_inv);
    k_prep_sup<<<C_WAY * K_SHOT * T_LEN, 256, 0, stream>>>(sup, supbf);
    k_proto<<<C_WAY * T_LEN, 256, 0, stream>>>(sup, protobf, pn_inv);
    k_qcond<<<Q * NW, 256, 0, stream>>>(query, qcondbf);
    k_supcond<<<C_WAY * NW, 256, 0, stream>>>(sup, scondbf);

    // SIM = query · protoᵀ  [Q*16, 160]
    {
        dim3 g(cdiv(Q * T_LEN, 64), cdiv(C_WAY * T_LEN, 64), 1);
        gemm_mfma<<<g, 256, 0, stream>>>(qbf, protobf, SIM, Q * T_LEN, C_WAY * T_LEN, D_DIM,
                                         nullptr, 0, nullptr, 0, 0);
    }
    // S_raw = qcond · cls_supᵀ  [Q*3, 1200]
    {
        dim3 g(cdiv(Q * NW, 64), cdiv(C_WAY * NW * 40, 64), 1);
        gemm_mfma<<<g, 256, 0, stream>>>(qcondbf, supbf, Sraw, Q * NW, C_WAY * NW * 40, D_DIM,
                                         nullptr, 0, map_cls, 0, 0);
    }
    // Q_raw = q_seg · scondᵀ  [Q*24, 30]
    {
        dim3 g(cdiv(Q * NW * SEG_L, 64), 1, 1);
        gemm_mfma<<<g, 256, 0, stream>>>(qbf, scondbf, Qraw, Q * NW * SEG_L, C_WAY * NW, D_DIM,
                                         map_qseg, 0, nullptr, 0, 0);
    }
    // G_sup[b] = cls_sup[b] · cls_sup[b]ᵀ, b over 30 (c,w), 40×40 each
    {
        dim3 g(1, 1, C_WAY * NW);
        gemm_mfma<<<g, 256, 0, stream>>>(supbf, supbf, Gsup, 40, 40, D_DIM,
                                         map_cls, 40, map_cls, 40, 1600);
    }
    k_gq<<<Q * NW, 64, 0, stream>>>(query, Gq);
    k_greduce<<<Q, 256, 0, stream>>>(SIM, qrow_inv, pn_inv, gscore);
    k_final<<<Q * C_WAY, 64, 0, stream>>>(Sraw, Qraw, Gsup, Gq, gscore, fusion, out);
}

// Round 3
// 118.189 us; speedup vs baseline: 2.7475x; 1.2085x over previous
//
#include <hip/hip_runtime.h>
#include <math.h>

#define C_WAY 10
#define K_SHOT 5
#define T_LEN 16
#define D_DIM 1024
#define NW 3
#define SEG_L 8

typedef __attribute__((ext_vector_type(8))) __bf16 bf16x8;
typedef __attribute__((ext_vector_type(4))) float f32x4;

static inline int cdiv(int a, int b) { return (a + b - 1) / b; }

__device__ __forceinline__ unsigned short f2bf(float f) {
    unsigned int u = __float_as_uint(f);
    u += 0x7fffu + ((u >> 16) & 1u);
    return (unsigned short)(u >> 16);
}
__device__ __forceinline__ float bf2f(unsigned short b) {
    return __uint_as_float(((unsigned int)b) << 16);
}
__device__ __forceinline__ ushort4 f2bf4(float4 v) {
    ushort4 b = {f2bf(v.x), f2bf(v.y), f2bf(v.z), f2bf(v.w)};
    return b;
}

__device__ __forceinline__ float wsum(float v) {
#pragma unroll
    for (int o = 32; o; o >>= 1) v += __shfl_xor(v, o);
    return v;
}
__device__ __forceinline__ float wmax(float v) {
#pragma unroll
    for (int o = 32; o; o >>= 1) v = fmaxf(v, __shfl_xor(v, o));
    return v;
}
__device__ __forceinline__ float wsum8(float v) {
#pragma unroll
    for (int o = 4; o; o >>= 1) v += __shfl_xor(v, o);
    return v;
}
__device__ __forceinline__ float wmax8(float v) {
#pragma unroll
    for (int o = 4; o; o >>= 1) v = fmaxf(v, __shfl_xor(v, o));
    return v;
}

// ---- fused query prep: qbf (bf16 copy), qrow_inv, qcondbf. One block per q. ----
__global__ __launch_bounds__(256) void k_prep_q(const float* __restrict__ q,
                                                unsigned short* __restrict__ qbf,
                                                float* __restrict__ qrow_inv,
                                                unsigned short* __restrict__ qcondbf) {
    __shared__ float red[NW][4];
    int qq = blockIdx.x;
    int t = threadIdx.x, wv = t >> 6, lane = t & 63;
    // phase 1: bf16 convert + per-row norms; wave wv -> rows wv*4..wv*4+3
#pragma unroll
    for (int r0 = 0; r0 < 4; ++r0) {
        int row = qq * T_LEN + wv * 4 + r0;
        float sq = 0.f;
#pragma unroll
        for (int i = 0; i < 4; ++i) {
            float4 v = *(const float4*)&q[(size_t)row * D_DIM + (i * 64 + lane) * 4];
            *(ushort4*)&qbf[(size_t)row * D_DIM + (i * 64 + lane) * 4] = f2bf4(v);
            sq += v.x * v.x + v.y * v.y + v.z * v.z + v.w * v.w;
        }
        sq = wsum(sq);
        if (lane == 0) qrow_inv[row] = 1.0f / fmaxf(sqrtf(sq), 1e-12f);
    }
    __syncthreads();
    // phase 2: segment means from qbf (L1/L2 hot); thread t owns cols t*4..t*4+3
    for (int v = 0; v < NW; ++v) {
        float4 acc = {0.f, 0.f, 0.f, 0.f};
#pragma unroll
        for (int l = 0; l < SEG_L; ++l) {
            ushort4 b = *(const ushort4*)&qbf[((size_t)(qq * T_LEN + v * 4 + l)) * D_DIM + t * 4];
            acc.x += bf2f(b.x); acc.y += bf2f(b.y); acc.z += bf2f(b.z); acc.w += bf2f(b.w);
        }
        acc.x *= 0.125f; acc.y *= 0.125f; acc.z *= 0.125f; acc.w *= 0.125f;
        float sq = acc.x * acc.x + acc.y * acc.y + acc.z * acc.z + acc.w * acc.w;
        sq = wsum(sq);
        if (lane == 0) red[v][wv] = sq;
        __syncthreads();
        float tot = red[v][0] + red[v][1] + red[v][2] + red[v][3];
        float scl = 1.0f / fmaxf(sqrtf(tot), 1e-12f);
        float4 o = {acc.x * scl, acc.y * scl, acc.z * scl, acc.w * scl};
        *(ushort4*)&qcondbf[((size_t)(qq * NW + v)) * D_DIM + t * 4] = f2bf4(o);
        __syncthreads();
    }
}

// ---- fused support prep: supbf, protobf+pn_inv, scondbf. One block per class. ----
__global__ __launch_bounds__(256) void k_prep_s(const float* __restrict__ sup,
                                                unsigned short* __restrict__ supbf,
                                                unsigned short* __restrict__ protobf,
                                                float* __restrict__ pn_inv,
                                                unsigned short* __restrict__ scondbf) {
    int c = blockIdx.x;
    int wv = threadIdx.x >> 6, lane = threadIdx.x & 63;
    // supbf: 80 rows; wave wv -> rows wv*20..wv*20+19
    for (int r = 0; r < 20; ++r) {
        int row = c * 80 + wv * 20 + r;
#pragma unroll
        for (int i = 0; i < 4; ++i) {
            float4 v = *(const float4*)&sup[(size_t)row * D_DIM + (i * 64 + lane) * 4];
            *(ushort4*)&supbf[(size_t)row * D_DIM + (i * 64 + lane) * 4] = f2bf4(v);
        }
    }
    // proto rows: wave wv -> t = wv*4..wv*4+3
#pragma unroll
    for (int r0 = 0; r0 < 4; ++r0) {
        int tt = wv * 4 + r0;
        float4 a[4] = {};
        for (int k = 0; k < K_SHOT; ++k)
#pragma unroll
            for (int i = 0; i < 4; ++i) {
                float4 v = *(const float4*)&sup[((size_t)(c * 80 + k * 16 + tt)) * D_DIM + (i * 64 + lane) * 4];
                a[i].x += v.x; a[i].y += v.y; a[i].z += v.z; a[i].w += v.w;
            }
        float sq = 0.f;
#pragma unroll
        for (int i = 0; i < 4; ++i) {
            a[i].x *= 0.2f; a[i].y *= 0.2f; a[i].z *= 0.2f; a[i].w *= 0.2f;
            sq += a[i].x * a[i].x + a[i].y * a[i].y + a[i].z * a[i].z + a[i].w * a[i].w;
        }
        sq = wsum(sq);
        if (lane == 0) pn_inv[c * T_LEN + tt] = 1.0f / fmaxf(sqrtf(sq), 1e-12f);
#pragma unroll
        for (int i = 0; i < 4; ++i)
            *(ushort4*)&protobf[((size_t)(c * T_LEN + tt)) * D_DIM + (i * 64 + lane) * 4] = f2bf4(a[i]);
    }
    // scond: waves 0..2 handle w = wv
    if (wv < NW) {
        float4 a[4] = {};
        for (int k = 0; k < K_SHOT; ++k)
#pragma unroll
            for (int l = 0; l < SEG_L; ++l)
#pragma unroll
                for (int i = 0; i < 4; ++i) {
                    float4 v = *(const float4*)&sup[((size_t)(c * 80 + k * 16 + wv * 4 + l)) * D_DIM + (i * 64 + lane) * 4];
                    a[i].x += v.x; a[i].y += v.y; a[i].z += v.z; a[i].w += v.w;
                }
        float sq = 0.f;
        const float s = 1.0f / 40.0f;
#pragma unroll
        for (int i = 0; i < 4; ++i) {
            a[i].x *= s; a[i].y *= s; a[i].z *= s; a[i].w *= s;
            sq += a[i].x * a[i].x + a[i].y * a[i].y + a[i].z * a[i].z + a[i].w * a[i].w;
        }
        sq = wsum(sq);
        float scl = 1.0f / fmaxf(sqrtf(sq), 1e-12f);
#pragma unroll
        for (int i = 0; i < 4; ++i) {
            float4 o = {a[i].x * scl, a[i].y * scl, a[i].z * scl, a[i].w * scl};
            *(ushort4*)&scondbf[((size_t)(c * NW + wv)) * D_DIM + (i * 64 + lane) * 4] = f2bf4(o);
        }
    }
}

__global__ __launch_bounds__(256) void k_rowmaps(int* __restrict__ map_cls,
                                                 int* __restrict__ map_qseg, int Q) {
    int i = blockIdx.x * 256 + threadIdx.x;
    if (i < C_WAY * NW * 40) {
        int c = i / 120, rem = i % 120, w = rem / 40, n = rem % 40, k = n >> 3, l = n & 7;
        map_cls[i] = (c * K_SHOT + k) * T_LEN + w * 4 + l;
    }
    if (i < Q * NW * SEG_L) {
        int q = i / 24, rem = i % 24, v = rem / 8, l = rem & 7;
        map_qseg[i] = q * T_LEN + v * 4 + l;
    }
}

// C[b][m,n] = sum_k A[rowA(b,m), k] * B[rowB(b,n), k]  (bf16 inputs, fp32 accum)
__global__ __launch_bounds__(256) void gemm_mfma(const unsigned short* __restrict__ A,
                                                 const unsigned short* __restrict__ B,
                                                 float* __restrict__ C,
                                                 int M, int N, int K,
                                                 const int* __restrict__ mapA, int mapAs,
                                                 const int* __restrict__ mapB, int mapBs,
                                                 long cstride) {
    __shared__ __align__(16) unsigned short As[64][72];
    __shared__ __align__(16) unsigned short Bs[64][72];
    int b = blockIdx.z;
    float* Cb = C + (size_t)b * cstride;
    int m0 = blockIdx.x * 64, n0 = blockIdx.y * 64;
    int t = threadIdx.x;
    int srow = t >> 2, sk = (t & 3) * 8;
    long ga = -1, gb = -1;
    if (m0 + srow < M) ga = mapA ? mapA[(size_t)b * mapAs + m0 + srow] : (m0 + srow);
    if (n0 + srow < N) gb = mapB ? mapB[(size_t)b * mapBs + n0 + srow] : (n0 + srow);

    int w = t >> 6, l = t & 63;
    int rowbase = (w >> 1) * 32, colbase = (w & 1) * 32;
    int fr = l & 15, fc = l >> 4;

    f32x4 acc[2][2] = {};

    uint4 ra0 = {0, 0, 0, 0}, ra1 = {0, 0, 0, 0}, rb0 = {0, 0, 0, 0}, rb1 = {0, 0, 0, 0};
    if (ga >= 0) {
        ra0 = *(const uint4*)&A[(size_t)ga * K + sk];
        ra1 = *(const uint4*)&A[(size_t)ga * K + sk + 32];
    }
    if (gb >= 0) {
        rb0 = *(const uint4*)&B[(size_t)gb * K + sk];
        rb1 = *(const uint4*)&B[(size_t)gb * K + sk + 32];
    }
    for (int k0 = 0; k0 < K; k0 += 64) {
        __syncthreads();
        *(uint4*)&As[srow][sk] = ra0;
        *(uint4*)&As[srow][sk + 32] = ra1;
        *(uint4*)&Bs[srow][sk] = rb0;
        *(uint4*)&Bs[srow][sk + 32] = rb1;
        __syncthreads();
        int kn = k0 + 64;
        if (kn < K) {
            if (ga >= 0) {
                ra0 = *(const uint4*)&A[(size_t)ga * K + kn + sk];
                ra1 = *(const uint4*)&A[(size_t)ga * K + kn + sk + 32];
            }
            if (gb >= 0) {
                rb0 = *(const uint4*)&B[(size_t)gb * K + kn + sk];
                rb1 = *(const uint4*)&B[(size_t)gb * K + kn + sk + 32];
            }
        }
#pragma unroll
        for (int kk = 0; kk < 2; ++kk) {
            bf16x8 a0 = *(const bf16x8*)&As[rowbase + fr][kk * 32 + fc * 8];
            bf16x8 a1 = *(const bf16x8*)&As[rowbase + 16 + fr][kk * 32 + fc * 8];
            bf16x8 b0 = *(const bf16x8*)&Bs[colbase + fr][kk * 32 + fc * 8];
            bf16x8 b1 = *(const bf16x8*)&Bs[colbase + 16 + fr][kk * 32 + fc * 8];
            acc[0][0] = __builtin_amdgcn_mfma_f32_16x16x32_bf16(a0, b0, acc[0][0], 0, 0, 0);
            acc[0][1] = __builtin_amdgcn_mfma_f32_16x16x32_bf16(a0, b1, acc[0][1], 0, 0, 0);
            acc[1][0] = __builtin_amdgcn_mfma_f32_16x16x32_bf16(a1, b0, acc[1][0], 0, 0, 0);
            acc[1][1] = __builtin_amdgcn_mfma_f32_16x16x32_bf16(a1, b1, acc[1][1], 0, 0, 0);
        }
    }
    int crow = fc * 4, ccol = fr;
#pragma unroll
    for (int fi = 0; fi < 2; ++fi)
#pragma unroll
        for (int fj = 0; fj < 2; ++fj)
#pragma unroll
            for (int j = 0; j < 4; ++j) {
                int m = m0 + rowbase + fi * 16 + crow + j;
                int n = n0 + colbase + fj * 16 + ccol;
                if (m < M && n < N) Cb[(size_t)m * N + n] = acc[fi][fj][j];
            }
}

// ---- Gq via MFMA: each wave computes Gram matrices of TWO (q,v) pairs ----
__global__ __launch_bounds__(256) void k_gq_mfma(const unsigned short* __restrict__ qbf,
                                                 float* __restrict__ Gq, int QNW) {
    int gw = blockIdx.x * 4 + (threadIdx.x >> 6);
    int lane = threadIdx.x & 63;
    int qv0 = gw * 2, qv1 = gw * 2 + 1;
    if (qv0 >= QNW) return;
    int fr = lane & 15, fc = lane >> 4;
    int half = fr >> 3;
    int qv = (half && qv1 < QNW) ? qv1 : qv0;
    int row = (qv / 3) * T_LEN + (qv % 3) * 4 + (fr & 7);
    const unsigned short* src = qbf + (size_t)row * D_DIM + fc * 8;
    f32x4 acc = {};
    for (int k0 = 0; k0 < D_DIM; k0 += 32) {
        bf16x8 f = *(const bf16x8*)&src[k0];
        acc = __builtin_amdgcn_mfma_f32_16x16x32_bf16(f, f, acc, 0, 0, 0);
    }
    // C[i][j] = dot(row(i), row(j)); i = fc*4+jj, j = fr
    if (fr < 8 && fc < 2) {
#pragma unroll
        for (int jj = 0; jj < 4; ++jj) {
            int i = fc * 4 + jj;
            Gq[(size_t)qv0 * 64 + i * 8 + fr] = acc[jj];
        }
    }
    if (fr >= 8 && fc >= 2 && qv1 < QNW) {
#pragma unroll
        for (int jj = 0; jj < 4; ++jj) {
            int i = (fc - 2) * 4 + jj;
            Gq[(size_t)qv1 * 64 + i * 8 + (fr - 8)] = acc[jj];
        }
    }
}

// ---- fused final: global-branch tile reduce + segment branch. One wave per (q,c). ----
__global__ __launch_bounds__(64) void k_final2(const float* __restrict__ Sraw,
                                               const float* __restrict__ Qraw,
                                               const float* __restrict__ Gsup,
                                               const float* __restrict__ Gq,
                                               const float* __restrict__ SIM,
                                               const float* __restrict__ qrow_inv,
                                               const float* __restrict__ pn_inv,
                                               const float* __restrict__ fusion,
                                               float* __restrict__ out) {
    __shared__ __align__(16) float Gs[1600];
    __shared__ float ebuf[40];
    __shared__ float e8buf[8];
    __shared__ float dtile[16 * 17];
    __shared__ float qi_s[16], pi_s[16];
    int bid = blockIdx.x;
    int q = bid / 10, c = bid % 10;
    int lane = threadIdx.x;
    const float inv_sqrt_d = 0.03125f;

    // ---- global branch: min-reduce this (q,c)'s 16x16 SIM tile ----
    if (lane < 16) {
        qi_s[lane] = qrow_inv[q * 16 + lane];
        pi_s[lane] = pn_inv[c * 16 + lane];
    }
    __syncthreads();
    {
        int t = lane >> 2, s4 = (lane & 3) * 4;
        float4 sv = *(const float4*)&SIM[((size_t)(q * 16 + t)) * 160 + c * 16 + s4];
        float qi = qi_s[t];
        dtile[t * 17 + s4 + 0] = 1.0f - sv.x * qi * pi_s[s4 + 0];
        dtile[t * 17 + s4 + 1] = 1.0f - sv.y * qi * pi_s[s4 + 1];
        dtile[t * 17 + s4 + 2] = 1.0f - sv.z * qi * pi_s[s4 + 2];
        dtile[t * 17 + s4 + 3] = 1.0f - sv.w * qi * pi_s[s4 + 3];
    }
    __syncthreads();
    float gpart = 0.f;
    if (lane < 16) {
        float mn = 3.4e38f;
#pragma unroll
        for (int s = 0; s < 16; ++s) mn = fminf(mn, dtile[lane * 17 + s]);
        gpart = mn;
    } else if (lane < 32) {
        int s = lane - 16;
        float mn = 3.4e38f;
#pragma unroll
        for (int t = 0; t < 16; ++t) mn = fminf(mn, dtile[t * 17 + s]);
        gpart = mn;
    }
    float gscore = -wsum(gpart);

    // ---- segment branch ----
    float b1s = -3.4e38f, b2s = -3.4e38f, b1q = -3.4e38f, b2q = -3.4e38f;
    for (int w = 0; w < 3; ++w) {
        __syncthreads();
#pragma unroll
        for (int j = 0; j < 25; ++j)
            Gs[j * 64 + lane] = Gsup[(size_t)(c * 3 + w) * 1600 + j * 64 + lane];
        for (int v = 0; v < 3; ++v) {
            __syncthreads();
            // s2q: unnormalized softmax (denominator cancels in cosine)
            bool act = lane < 40;
            float raw = act ? Sraw[((size_t)(q * 3 + v)) * 1200 + (c * 3 + w) * 40 + lane] : 0.f;
            float x = act ? raw * inv_sqrt_d : -3.4e38f;
            float mx = wmax(x);
            float e = act ? __expf(x - mx) : 0.f;
            if (act) ebuf[lane] = e;
            float dot_e = wsum(e * raw);
            // q2s setup
            bool a8 = lane < 8;
            float qraw = a8 ? Qraw[((size_t)((q * 3 + v) * 8 + lane)) * 30 + c * 3 + w] : 0.f;
            float x8 = a8 ? qraw * inv_sqrt_d : -3.4e38f;
            float mx8 = wmax8(x8);
            float e8 = a8 ? __expf(x8 - mx8) : 0.f;
            if (a8) e8buf[lane] = e8;
            float dot8 = wsum8(e8 * qraw);
            __syncthreads();
            // s2q quadratic form over triangular half (820 elems, 13/lane)
            float acc = 0.f;
#pragma unroll
            for (int j = 0; j < 13; ++j) {
                int i = j * 64 + lane;
                if (i < 820) {
                    float fi = (float)(8 * i + 1);
                    int m = (int)((sqrtf(fi) - 1.0f) * 0.5f);
                    int n = i - ((m * (m + 1)) >> 1);
                    float prod = ebuf[m] * ebuf[n] * Gs[m * 40 + n];
                    acc += (m == n) ? prod : 2.0f * prod;
                }
            }
            float quad = wsum(acc);
            float sc = dot_e / sqrtf(quad);
            // q2s quadratic form: 1 elem/lane
            int mm = lane >> 3, nn = lane & 7;
            float q2 = e8buf[mm] * e8buf[nn] * Gq[(size_t)(q * 3 + v) * 64 + lane];
            q2 = wsum(q2);
            float sc8 = __shfl(dot8, 0) / sqrtf(q2);
            // top-2 tracking
            if (sc > b1s) { b2s = b1s; b1s = sc; } else if (sc > b2s) b2s = sc;
            if (sc8 > b1q) { b2q = b1q; b1q = sc8; } else if (sc8 > b2q) b2q = sc8;
        }
    }
    if (lane == 0) {
        float seg = 0.5f * (0.5f * (b1s + b2s) + 0.5f * (b1q + b2q));
        float l0 = fusion[0], l1 = fusion[1];
        float mmx = fmaxf(l0, l1);
        float e0 = __expf(l0 - mmx), e1 = __expf(l1 - mmx);
        float f0 = e0 / (e0 + e1), f1 = e1 / (e0 + e1);
        out[bid] = f0 * gscore + f1 * seg;
    }
}

extern "C" void kernel_launch(void* const* d_in, const int* in_sizes, int n_in,
                              void* d_out, int out_size, void* d_ws, size_t ws_size,
                              hipStream_t stream) {
    const float* sup = (const float*)d_in[0];    // [50,16,1024]
    const float* query = (const float*)d_in[1];  // [400,16,1024]
    const float* fusion = (const float*)d_in[2]; // [2]
    float* out = (float*)d_out;                  // [400,10]
    const int Q = in_sizes[1] / (T_LEN * D_DIM); // 400

    float* w = (float*)d_ws;
    size_t off = 0;
    unsigned short* qbf = (unsigned short*)(w + off);     off += (size_t)Q * T_LEN * D_DIM / 2;
    unsigned short* supbf = (unsigned short*)(w + off);   off += (size_t)C_WAY * K_SHOT * T_LEN * D_DIM / 2;
    unsigned short* protobf = (unsigned short*)(w + off); off += (size_t)C_WAY * T_LEN * D_DIM / 2;
    unsigned short* qcondbf = (unsigned short*)(w + off); off += (size_t)Q * NW * D_DIM / 2;
    unsigned short* scondbf = (unsigned short*)(w + off); off += (size_t)C_WAY * NW * D_DIM / 2 + 8;
    float* pn_inv = w + off;    off += C_WAY * T_LEN;
    float* qrow_inv = w + off;  off += (size_t)Q * T_LEN;
    float* Gsup = w + off;      off += C_WAY * NW * 40 * 40;
    float* Gq = w + off;        off += (size_t)Q * NW * 64;
    float* SIM = w + off;       off += (size_t)Q * T_LEN * C_WAY * T_LEN;
    float* Sraw = w + off;      off += (size_t)Q * NW * C_WAY * NW * 40;
    float* Qraw = w + off;      off += (size_t)Q * NW * SEG_L * C_WAY * NW;
    int* map_cls = (int*)(w + off);  off += C_WAY * NW * 40;
    int* map_qseg = (int*)(w + off); off += (size_t)Q * NW * SEG_L;
    (void)ws_size; (void)n_in; (void)out_size;

    k_rowmaps<<<cdiv(Q * NW * SEG_L, 256), 256, 0, stream>>>(map_cls, map_qseg, Q);
    k_prep_q<<<Q, 256, 0, stream>>>(query, qbf, qrow_inv, qcondbf);
    k_prep_s<<<C_WAY, 256, 0, stream>>>(sup, supbf, protobf, pn_inv, scondbf);

    // SIM = query · protoᵀ  [Q*16, 160]
    {
        dim3 g(cdiv(Q * T_LEN, 64), cdiv(C_WAY * T_LEN, 64), 1);
        gemm_mfma<<<g, 256, 0, stream>>>(qbf, protobf, SIM, Q * T_LEN, C_WAY * T_LEN, D_DIM,
                                         nullptr, 0, nullptr, 0, 0);
    }
    // S_raw = qcond · cls_supᵀ  [Q*3, 1200]
    {
        dim3 g(cdiv(Q * NW, 64), cdiv(C_WAY * NW * 40, 64), 1);
        gemm_mfma<<<g, 256, 0, stream>>>(qcondbf, supbf, Sraw, Q * NW, C_WAY * NW * 40, D_DIM,
                                         nullptr, 0, map_cls, 0, 0);
    }
    // Q_raw = q_seg · scondᵀ  [Q*24, 30]
    {
        dim3 g(cdiv(Q * NW * SEG_L, 64), 1, 1);
        gemm_mfma<<<g, 256, 0, stream>>>(qbf, scondbf, Qraw, Q * NW * SEG_L, C_WAY * NW, D_DIM,
                                         map_qseg, 0, nullptr, 0, 0);
    }
    // G_sup[b] = cls_sup[b] · cls_sup[b]ᵀ, b over 30 (c,w)
    {
        dim3 g(1, 1, C_WAY * NW);
        gemm_mfma<<<g, 256, 0, stream>>>(supbf, supbf, Gsup, 40, 40, D_DIM,
                                         map_cls, 40, map_cls, 40, 1600);
    }
    k_gq_mfma<<<cdiv(Q * NW, 8), 256, 0, stream>>>(qbf, Gq, Q * NW);
    k_final2<<<Q * C_WAY, 64, 0, stream>>>(Sraw, Qraw, Gsup, Gq, SIM, qrow_inv, pn_inv,
                                           fusion, out);
}

// Round 4
// 75.331 us; speedup vs baseline: 4.3106x; 1.5689x over previous
//
#include <hip/hip_runtime.h>
#include <math.h>

#define C_WAY 10
#define K_SHOT 5
#define T_LEN 16
#define D_DIM 1024
#define NW 3
#define SEG_L 8

typedef __attribute__((ext_vector_type(8))) __bf16 bf16x8;
typedef __attribute__((ext_vector_type(4))) float f32x4;

static inline int cdiv(int a, int b) { return (a + b - 1) / b; }

__device__ __forceinline__ unsigned short f2bf(float f) {
    unsigned int u = __float_as_uint(f);
    u += 0x7fffu + ((u >> 16) & 1u);
    return (unsigned short)(u >> 16);
}
__device__ __forceinline__ float bf2f(unsigned short b) {
    return __uint_as_float(((unsigned int)b) << 16);
}
__device__ __forceinline__ ushort4 f2bf4(float4 v) {
    ushort4 b = {f2bf(v.x), f2bf(v.y), f2bf(v.z), f2bf(v.w)};
    return b;
}

__device__ __forceinline__ float wsum(float v) {
#pragma unroll
    for (int o = 32; o; o >>= 1) v += __shfl_xor(v, o);
    return v;
}
__device__ __forceinline__ float wmax(float v) {
#pragma unroll
    for (int o = 32; o; o >>= 1) v = fmaxf(v, __shfl_xor(v, o));
    return v;
}
__device__ __forceinline__ float wsum8(float v) {
#pragma unroll
    for (int o = 4; o; o >>= 1) v += __shfl_xor(v, o);
    return v;
}
__device__ __forceinline__ float wmax8(float v) {
#pragma unroll
    for (int o = 4; o; o >>= 1) v = fmaxf(v, __shfl_xor(v, o));
    return v;
}

// row-index maps (inline arithmetic; replaces map arrays)
__device__ __forceinline__ int cls_row(int i) {  // i in [0, 1200)
    int c = i / 120, rem = i - c * 120;
    int w = rem / 40, tok = rem - w * 40;
    return c * 80 + (tok >> 3) * 16 + w * 4 + (tok & 7);
}
__device__ __forceinline__ int qseg_row(int m) {  // m in [0, Q*24)
    int q = m / 24, rem = m - q * 24;
    return q * 16 + (rem >> 3) * 4 + (rem & 7);
}

// ================= fused prep =================
// blocks [0,Q): per-q bf16 convert + row norms + qcond
// blocks [Q,Q+50): per-support-sample bf16 convert
// blocks [Q+50,Q+60): per-class proto + pn_inv + scond
__global__ __launch_bounds__(256) void k_prep(const float* __restrict__ sup,
                                              const float* __restrict__ query,
                                              unsigned short* __restrict__ qbf,
                                              float* __restrict__ qrow_inv,
                                              unsigned short* __restrict__ qcondbf,
                                              unsigned short* __restrict__ supbf,
                                              unsigned short* __restrict__ protobf,
                                              float* __restrict__ pn_inv,
                                              unsigned short* __restrict__ scondbf,
                                              int Q) {
    __shared__ float red[NW][4];
    int b = blockIdx.x;
    int t = threadIdx.x, wv = t >> 6, lane = t & 63;
    if (b < Q) {
        int qq = b;
#pragma unroll
        for (int r0 = 0; r0 < 4; ++r0) {
            int row = qq * T_LEN + wv * 4 + r0;
            float sq = 0.f;
#pragma unroll
            for (int i = 0; i < 4; ++i) {
                float4 v = *(const float4*)&query[(size_t)row * D_DIM + (i * 64 + lane) * 4];
                *(ushort4*)&qbf[(size_t)row * D_DIM + (i * 64 + lane) * 4] = f2bf4(v);
                sq += v.x * v.x + v.y * v.y + v.z * v.z + v.w * v.w;
            }
            sq = wsum(sq);
            if (lane == 0) qrow_inv[row] = 1.0f / fmaxf(sqrtf(sq), 1e-12f);
        }
        __syncthreads();
        for (int v = 0; v < NW; ++v) {
            float4 acc = {0.f, 0.f, 0.f, 0.f};
#pragma unroll
            for (int l = 0; l < SEG_L; ++l) {
                ushort4 bb = *(const ushort4*)&qbf[((size_t)(qq * T_LEN + v * 4 + l)) * D_DIM + t * 4];
                acc.x += bf2f(bb.x); acc.y += bf2f(bb.y); acc.z += bf2f(bb.z); acc.w += bf2f(bb.w);
            }
            acc.x *= 0.125f; acc.y *= 0.125f; acc.z *= 0.125f; acc.w *= 0.125f;
            float sq = acc.x * acc.x + acc.y * acc.y + acc.z * acc.z + acc.w * acc.w;
            sq = wsum(sq);
            if (lane == 0) red[v][wv] = sq;
            __syncthreads();
            float tot = red[v][0] + red[v][1] + red[v][2] + red[v][3];
            float scl = 1.0f / fmaxf(sqrtf(tot), 1e-12f);
            float4 o = {acc.x * scl, acc.y * scl, acc.z * scl, acc.w * scl};
            *(ushort4*)&qcondbf[((size_t)(qq * NW + v)) * D_DIM + t * 4] = f2bf4(o);
            __syncthreads();
        }
    } else if (b < Q + C_WAY * K_SHOT) {
        int s = b - Q;  // support sample
#pragma unroll
        for (int i = 0; i < 16; ++i) {
            int qd = i * 256 + t;  // quad index within 16x1024 sample
            float4 v = *(const float4*)&sup[(size_t)s * 16384 + qd * 4];
            *(ushort4*)&supbf[(size_t)s * 16384 + qd * 4] = f2bf4(v);
        }
    } else {
        int c = b - Q - C_WAY * K_SHOT;
        // proto rows: wave wv -> t = wv*4..wv*4+3
#pragma unroll
        for (int r0 = 0; r0 < 4; ++r0) {
            int tt = wv * 4 + r0;
            float4 a[4] = {};
            for (int k = 0; k < K_SHOT; ++k)
#pragma unroll
                for (int i = 0; i < 4; ++i) {
                    float4 v = *(const float4*)&sup[((size_t)(c * 80 + k * 16 + tt)) * D_DIM + (i * 64 + lane) * 4];
                    a[i].x += v.x; a[i].y += v.y; a[i].z += v.z; a[i].w += v.w;
                }
            float sq = 0.f;
#pragma unroll
            for (int i = 0; i < 4; ++i) {
                a[i].x *= 0.2f; a[i].y *= 0.2f; a[i].z *= 0.2f; a[i].w *= 0.2f;
                sq += a[i].x * a[i].x + a[i].y * a[i].y + a[i].z * a[i].z + a[i].w * a[i].w;
            }
            sq = wsum(sq);
            if (lane == 0) pn_inv[c * T_LEN + tt] = 1.0f / fmaxf(sqrtf(sq), 1e-12f);
#pragma unroll
            for (int i = 0; i < 4; ++i)
                *(ushort4*)&protobf[((size_t)(c * T_LEN + tt)) * D_DIM + (i * 64 + lane) * 4] = f2bf4(a[i]);
        }
        if (wv < NW) {
            float4 a[4] = {};
            for (int k = 0; k < K_SHOT; ++k)
#pragma unroll
                for (int l = 0; l < SEG_L; ++l)
#pragma unroll
                    for (int i = 0; i < 4; ++i) {
                        float4 v = *(const float4*)&sup[((size_t)(c * 80 + k * 16 + wv * 4 + l)) * D_DIM + (i * 64 + lane) * 4];
                        a[i].x += v.x; a[i].y += v.y; a[i].z += v.z; a[i].w += v.w;
                    }
            float sq = 0.f;
            const float s = 1.0f / 40.0f;
#pragma unroll
            for (int i = 0; i < 4; ++i) {
                a[i].x *= s; a[i].y *= s; a[i].z *= s; a[i].w *= s;
                sq += a[i].x * a[i].x + a[i].y * a[i].y + a[i].z * a[i].z + a[i].w * a[i].w;
            }
            sq = wsum(sq);
            float scl = 1.0f / fmaxf(sqrtf(sq), 1e-12f);
#pragma unroll
            for (int i = 0; i < 4; ++i) {
                float4 o = {a[i].x * scl, a[i].y * scl, a[i].z * scl, a[i].w * scl};
                *(ushort4*)&scondbf[((size_t)(c * NW + wv)) * D_DIM + (i * 64 + lane) * 4] = f2bf4(o);
            }
        }
    }
}

// ================= GEMM tile core =================
// AM/BM: 0=direct row, 1=qseg map (A) / cls map (B), 2=cls map with batch
template <int AM, int BM>
__device__ __forceinline__ void gemm_tile(const unsigned short* __restrict__ A,
                                          const unsigned short* __restrict__ B,
                                          float* __restrict__ Cb,
                                          int M, int N, int m0, int n0, int batch,
                                          unsigned short (&As)[64][72],
                                          unsigned short (&Bs)[64][72]) {
    int t = threadIdx.x;
    int srow = t >> 2, sk = (t & 3) * 8;
    long ga = -1, gb = -1;
    int am = m0 + srow;
    if (am < M) ga = (AM == 0) ? am : (AM == 1 ? qseg_row(am) : cls_row(batch * 40 + am));
    int bn = n0 + srow;
    if (bn < N) gb = (BM == 0) ? bn : (BM == 1 ? cls_row(bn) : cls_row(batch * 40 + bn));

    int w = t >> 6, l = t & 63;
    int rowbase = (w >> 1) * 32, colbase = (w & 1) * 32;
    int fr = l & 15, fc = l >> 4;

    f32x4 acc[2][2] = {};
    uint4 ra0 = {0, 0, 0, 0}, ra1 = {0, 0, 0, 0}, rb0 = {0, 0, 0, 0}, rb1 = {0, 0, 0, 0};
    if (ga >= 0) {
        ra0 = *(const uint4*)&A[(size_t)ga * D_DIM + sk];
        ra1 = *(const uint4*)&A[(size_t)ga * D_DIM + sk + 32];
    }
    if (gb >= 0) {
        rb0 = *(const uint4*)&B[(size_t)gb * D_DIM + sk];
        rb1 = *(const uint4*)&B[(size_t)gb * D_DIM + sk + 32];
    }
    for (int k0 = 0; k0 < D_DIM; k0 += 64) {
        __syncthreads();
        *(uint4*)&As[srow][sk] = ra0;
        *(uint4*)&As[srow][sk + 32] = ra1;
        *(uint4*)&Bs[srow][sk] = rb0;
        *(uint4*)&Bs[srow][sk + 32] = rb1;
        __syncthreads();
        int kn = k0 + 64;
        if (kn < D_DIM) {
            if (ga >= 0) {
                ra0 = *(const uint4*)&A[(size_t)ga * D_DIM + kn + sk];
                ra1 = *(const uint4*)&A[(size_t)ga * D_DIM + kn + sk + 32];
            }
            if (gb >= 0) {
                rb0 = *(const uint4*)&B[(size_t)gb * D_DIM + kn + sk];
                rb1 = *(const uint4*)&B[(size_t)gb * D_DIM + kn + sk + 32];
            }
        }
#pragma unroll
        for (int kk = 0; kk < 2; ++kk) {
            bf16x8 a0 = *(const bf16x8*)&As[rowbase + fr][kk * 32 + fc * 8];
            bf16x8 a1 = *(const bf16x8*)&As[rowbase + 16 + fr][kk * 32 + fc * 8];
            bf16x8 b0 = *(const bf16x8*)&Bs[colbase + fr][kk * 32 + fc * 8];
            bf16x8 b1 = *(const bf16x8*)&Bs[colbase + 16 + fr][kk * 32 + fc * 8];
            acc[0][0] = __builtin_amdgcn_mfma_f32_16x16x32_bf16(a0, b0, acc[0][0], 0, 0, 0);
            acc[0][1] = __builtin_amdgcn_mfma_f32_16x16x32_bf16(a0, b1, acc[0][1], 0, 0, 0);
            acc[1][0] = __builtin_amdgcn_mfma_f32_16x16x32_bf16(a1, b0, acc[1][0], 0, 0, 0);
            acc[1][1] = __builtin_amdgcn_mfma_f32_16x16x32_bf16(a1, b1, acc[1][1], 0, 0, 0);
        }
    }
    int crow = fc * 4, ccol = fr;
#pragma unroll
    for (int fi = 0; fi < 2; ++fi)
#pragma unroll
        for (int fj = 0; fj < 2; ++fj)
#pragma unroll
            for (int j = 0; j < 4; ++j) {
                int m = m0 + rowbase + fi * 16 + crow + j;
                int n = n0 + colbase + fj * 16 + ccol;
                if (m < M && n < N) Cb[(size_t)m * N + n] = acc[fi][fj][j];
            }
}

// ================= mega: all 4 GEMMs + Gq in one launch =================
__global__ __launch_bounds__(256) void k_mega(const unsigned short* __restrict__ qbf,
                                              const unsigned short* __restrict__ protobf,
                                              const unsigned short* __restrict__ qcondbf,
                                              const unsigned short* __restrict__ supbf,
                                              const unsigned short* __restrict__ scondbf,
                                              float* __restrict__ SIM,
                                              float* __restrict__ Sraw,
                                              float* __restrict__ Qraw,
                                              float* __restrict__ Gsup,
                                              float* __restrict__ Gq,
                                              int Q, int mt0, int nb0, int mt1, int nb1,
                                              int nb2, int nb3) {
    __shared__ __align__(16) unsigned short As[64][72];
    __shared__ __align__(16) unsigned short Bs[64][72];
    int bid = blockIdx.x;
    if (bid < nb0) {  // SIM = qbf · protoᵀ [Q*16, 160]
        int mtile = bid % mt0, ntile = bid / mt0;
        gemm_tile<0, 0>(qbf, protobf, SIM, Q * T_LEN, 160, mtile * 64, ntile * 64, 0, As, Bs);
    } else if (bid < nb0 + nb1) {  // Sraw = qcond · cls_supᵀ [Q*3, 1200]
        int b2 = bid - nb0;
        int mtile = b2 % mt1, ntile = b2 / mt1;
        gemm_tile<0, 1>(qcondbf, supbf, Sraw, Q * NW, 1200, mtile * 64, ntile * 64, 0, As, Bs);
    } else if (bid < nb0 + nb1 + nb2) {  // Qraw = q_seg · scondᵀ [Q*24, 30]
        int mtile = bid - nb0 - nb1;
        gemm_tile<1, 0>(qbf, scondbf, Qraw, Q * 24, 30, mtile * 64, 0, 0, As, Bs);
    } else if (bid < nb0 + nb1 + nb2 + nb3) {  // Gsup[b] 40x40
        int batch = bid - nb0 - nb1 - nb2;
        gemm_tile<2, 2>(supbf, supbf, Gsup + (size_t)batch * 1600, 40, 40, 0, 0, batch, As, Bs);
    } else {  // Gq: each wave does two (q,v) Gram matrices
        int idx = bid - nb0 - nb1 - nb2 - nb3;
        int gw = idx * 4 + (threadIdx.x >> 6);
        int lane = threadIdx.x & 63;
        int QNW = Q * NW;
        int qv0 = gw * 2, qv1 = gw * 2 + 1;
        if (qv0 >= QNW) return;
        int fr = lane & 15, fc = lane >> 4;
        int half = fr >> 3;
        int qv = (half && qv1 < QNW) ? qv1 : qv0;
        int row = (qv / 3) * T_LEN + (qv % 3) * 4 + (fr & 7);
        const unsigned short* src = qbf + (size_t)row * D_DIM + fc * 8;
        f32x4 acc = {};
        for (int k0 = 0; k0 < D_DIM; k0 += 32) {
            bf16x8 f = *(const bf16x8*)&src[k0];
            acc = __builtin_amdgcn_mfma_f32_16x16x32_bf16(f, f, acc, 0, 0, 0);
        }
        if (fr < 8 && fc < 2) {
#pragma unroll
            for (int jj = 0; jj < 4; ++jj)
                Gq[(size_t)qv0 * 64 + (fc * 4 + jj) * 8 + fr] = acc[jj];
        }
        if (fr >= 8 && fc >= 2 && qv1 < QNW) {
#pragma unroll
            for (int jj = 0; jj < 4; ++jj)
                Gq[(size_t)qv1 * 64 + ((fc - 2) * 4 + jj) * 8 + (fr - 8)] = acc[jj];
        }
    }
}

// ================= fused final =================
__global__ __launch_bounds__(64) void k_final2(const float* __restrict__ Sraw,
                                               const float* __restrict__ Qraw,
                                               const float* __restrict__ Gsup,
                                               const float* __restrict__ Gq,
                                               const float* __restrict__ SIM,
                                               const float* __restrict__ qrow_inv,
                                               const float* __restrict__ pn_inv,
                                               const float* __restrict__ fusion,
                                               float* __restrict__ out) {
    __shared__ __align__(16) float Gs[1600];
    __shared__ float ebuf[40];
    __shared__ float e8buf[8];
    __shared__ float dtile[16 * 17];
    __shared__ float qi_s[16], pi_s[16];
    int bid = blockIdx.x;
    int q = bid / 10, c = bid % 10;
    int lane = threadIdx.x;
    const float inv_sqrt_d = 0.03125f;

    if (lane < 16) {
        qi_s[lane] = qrow_inv[q * 16 + lane];
        pi_s[lane] = pn_inv[c * 16 + lane];
    }
    __syncthreads();
    {
        int t = lane >> 2, s4 = (lane & 3) * 4;
        float4 sv = *(const float4*)&SIM[((size_t)(q * 16 + t)) * 160 + c * 16 + s4];
        float qi = qi_s[t];
        dtile[t * 17 + s4 + 0] = 1.0f - sv.x * qi * pi_s[s4 + 0];
        dtile[t * 17 + s4 + 1] = 1.0f - sv.y * qi * pi_s[s4 + 1];
        dtile[t * 17 + s4 + 2] = 1.0f - sv.z * qi * pi_s[s4 + 2];
        dtile[t * 17 + s4 + 3] = 1.0f - sv.w * qi * pi_s[s4 + 3];
    }
    __syncthreads();
    float gpart = 0.f;
    if (lane < 16) {
        float mn = 3.4e38f;
#pragma unroll
        for (int s = 0; s < 16; ++s) mn = fminf(mn, dtile[lane * 17 + s]);
        gpart = mn;
    } else if (lane < 32) {
        int s = lane - 16;
        float mn = 3.4e38f;
#pragma unroll
        for (int t = 0; t < 16; ++t) mn = fminf(mn, dtile[t * 17 + s]);
        gpart = mn;
    }
    float gscore = -wsum(gpart);

    float b1s = -3.4e38f, b2s = -3.4e38f, b1q = -3.4e38f, b2q = -3.4e38f;
    for (int w = 0; w < 3; ++w) {
        __syncthreads();
#pragma unroll
        for (int j = 0; j < 25; ++j)
            Gs[j * 64 + lane] = Gsup[(size_t)(c * 3 + w) * 1600 + j * 64 + lane];
        for (int v = 0; v < 3; ++v) {
            __syncthreads();
            bool act = lane < 40;
            float raw = act ? Sraw[((size_t)(q * 3 + v)) * 1200 + (c * 3 + w) * 40 + lane] : 0.f;
            float x = act ? raw * inv_sqrt_d : -3.4e38f;
            float mx = wmax(x);
            float e = act ? __expf(x - mx) : 0.f;
            if (act) ebuf[lane] = e;
            float dot_e = wsum(e * raw);
            bool a8 = lane < 8;
            float qraw = a8 ? Qraw[((size_t)((q * 3 + v) * 8 + lane)) * 30 + c * 3 + w] : 0.f;
            float x8 = a8 ? qraw * inv_sqrt_d : -3.4e38f;
            float mx8 = wmax8(x8);
            float e8 = a8 ? __expf(x8 - mx8) : 0.f;
            if (a8) e8buf[lane] = e8;
            float dot8 = wsum8(e8 * qraw);
            __syncthreads();
            // quadratic form over full 40x40 (1600 elems, 25/lane, magic div by 40)
            float acc = 0.f;
#pragma unroll
            for (int j = 0; j < 25; ++j) {
                int i = j * 64 + lane;
                int m = (i * 52429) >> 21;
                int n = i - m * 40;
                acc = fmaf(ebuf[m] * ebuf[n], Gs[i], acc);
            }
            float quad = wsum(acc);
            float sc = dot_e / sqrtf(quad);
            int mm = lane >> 3, nn = lane & 7;
            float q2 = e8buf[mm] * e8buf[nn] * Gq[(size_t)(q * 3 + v) * 64 + lane];
            q2 = wsum(q2);
            float sc8 = __shfl(dot8, 0) / sqrtf(q2);
            if (sc > b1s) { b2s = b1s; b1s = sc; } else if (sc > b2s) b2s = sc;
            if (sc8 > b1q) { b2q = b1q; b1q = sc8; } else if (sc8 > b2q) b2q = sc8;
        }
    }
    if (lane == 0) {
        float seg = 0.5f * (0.5f * (b1s + b2s) + 0.5f * (b1q + b2q));
        float l0 = fusion[0], l1 = fusion[1];
        float mmx = fmaxf(l0, l1);
        float e0 = __expf(l0 - mmx), e1 = __expf(l1 - mmx);
        float f0 = e0 / (e0 + e1), f1 = e1 / (e0 + e1);
        out[bid] = f0 * gscore + f1 * seg;
    }
}

extern "C" void kernel_launch(void* const* d_in, const int* in_sizes, int n_in,
                              void* d_out, int out_size, void* d_ws, size_t ws_size,
                              hipStream_t stream) {
    const float* sup = (const float*)d_in[0];    // [50,16,1024]
    const float* query = (const float*)d_in[1];  // [400,16,1024]
    const float* fusion = (const float*)d_in[2]; // [2]
    float* out = (float*)d_out;                  // [400,10]
    const int Q = in_sizes[1] / (T_LEN * D_DIM); // 400

    float* w = (float*)d_ws;
    size_t off = 0;
    unsigned short* qbf = (unsigned short*)(w + off);     off += (size_t)Q * T_LEN * D_DIM / 2;
    unsigned short* supbf = (unsigned short*)(w + off);   off += (size_t)C_WAY * K_SHOT * T_LEN * D_DIM / 2;
    unsigned short* protobf = (unsigned short*)(w + off); off += (size_t)C_WAY * T_LEN * D_DIM / 2;
    unsigned short* qcondbf = (unsigned short*)(w + off); off += (size_t)Q * NW * D_DIM / 2;
    unsigned short* scondbf = (unsigned short*)(w + off); off += (size_t)C_WAY * NW * D_DIM / 2 + 8;
    float* pn_inv = w + off;    off += C_WAY * T_LEN;
    float* qrow_inv = w + off;  off += (size_t)Q * T_LEN;
    float* Gsup = w + off;      off += C_WAY * NW * 40 * 40;
    float* Gq = w + off;        off += (size_t)Q * NW * 64;
    float* SIM = w + off;       off += (size_t)Q * T_LEN * C_WAY * T_LEN;
    float* Sraw = w + off;      off += (size_t)Q * NW * C_WAY * NW * 40;
    float* Qraw = w + off;      off += (size_t)Q * NW * SEG_L * C_WAY * NW;
    (void)ws_size; (void)n_in; (void)out_size;

    // 1) fused prep: Q + 50 + 10 blocks
    k_prep<<<Q + C_WAY * K_SHOT + C_WAY, 256, 0, stream>>>(
        sup, query, qbf, qrow_inv, qcondbf, supbf, protobf, pn_inv, scondbf, Q);

    // 2) mega: all GEMMs + Gq
    int mt0 = cdiv(Q * T_LEN, 64), nb0 = mt0 * cdiv(160, 64);
    int mt1 = cdiv(Q * NW, 64), nb1 = mt1 * cdiv(1200, 64);
    int nb2 = cdiv(Q * 24, 64);
    int nb3 = C_WAY * NW;
    int ngq = cdiv(Q * NW, 8);
    k_mega<<<nb0 + nb1 + nb2 + nb3 + ngq, 256, 0, stream>>>(
        qbf, protobf, qcondbf, supbf, scondbf, SIM, Sraw, Qraw, Gsup, Gq,
        Q, mt0, nb0, mt1, nb1, nb2, nb3);

    // 3) fused final
    k_final2<<<Q * C_WAY, 64, 0, stream>>>(Sraw, Qraw, Gsup, Gq, SIM, qrow_inv, pn_inv,
                                           fusion, out);
}